// Round 5
// baseline (458.949 us; speedup 1.0000x reference)
//
#include <hip/hip_runtime.h>
#include <hip/hip_bf16.h>

// Problem constants (from reference)
#define SCREEN_W 1280
#define SCREEN_H 720
#define TILE_L   16
#define NBW      80    // ceil(1280/16)
#define NBH      45    // ceil(720/16)
#define NUM_TILE 3600  // 80*45
#define N_POINTS 32768

// native clang vector type — required by __builtin_nontemporal_store
typedef int v4i __attribute__((ext_vector_type(4)));

// ---------------------------------------------------------------------------
// Kernel A: per-point tile-index ranges packed into one u32:
//   ximin | ximax<<8 | yimin<<16 | yimax<<24   (half-open: ximin <= xi < ximax)
// overlap_x(tile xi) <=> xmax > 16*xi && 16*xi+16 > xmin
//                    <=> (xmin>>4) <= xi < ((xmax+15)>>4)   [verified R4: absmax 0]
// Pixel AABB matches jnp.clip(v,0,lim).astype(int32) (truncation; all >= 0).
// Table: 32768 * 4 B = 128 KB in d_ws.
// ---------------------------------------------------------------------------
__global__ void aabb_kernel(const float* __restrict__ pos2d,
                            const float* __restrict__ radius,
                            unsigned int* __restrict__ pk) {
    int t = blockIdx.x * blockDim.x + threadIdx.x;   // thread handles 4 points
    int n = t * 4;
    if (n >= N_POINTS) return;

    const float4* p4 = (const float4*)(pos2d + 2 * n);
    float4 p01 = p4[0];   // x0 y0 x1 y1
    float4 p23 = p4[1];   // x2 y2 x3 y3
    float4 r   = *(const float4*)(radius + n);

    float xs[4] = {p01.x, p01.z, p23.x, p23.z};
    float ys[4] = {p01.y, p01.w, p23.y, p23.w};
    float rs[4] = {r.x, r.y, r.z, r.w};

    uint4 outp;
    unsigned int* op = &outp.x;
#pragma unroll
    for (int j = 0; j < 4; ++j) {
        float x = xs[j], y = ys[j], rr = rs[j];
        int xmin = (int)fminf(fmaxf(x - rr, 0.0f), (float)SCREEN_W);
        int ymin = (int)fminf(fmaxf(y - rr, 0.0f), (float)SCREEN_H);
        int xmax = (int)fminf(fmaxf(x + rr, 0.0f), (float)SCREEN_W);
        int ymax = (int)fminf(fmaxf(y + rr, 0.0f), (float)SCREEN_H);
        unsigned int ximin = (unsigned int)(xmin >> 4);          // <= 80
        unsigned int ximax = (unsigned int)((xmax + 15) >> 4);   // <= 80
        unsigned int yimin = (unsigned int)(ymin >> 4);          // <= 45
        unsigned int yimax = (unsigned int)((ymax + 15) >> 4);   // <= 45
        op[j] = ximin | (ximax << 8) | (yimin << 16) | (yimax << 24);
    }
    *(uint4*)(pk + n) = outp;   // one dwordx4 store for 4 points
}

// ---------------------------------------------------------------------------
// Kernel B: grid = (32 point-chunks, 80 xi). Each thread loads ONE uint4
// (4 packed points) once, builds a per-point 45-bit y-interval bitmask with
// the x-test folded in (mask = 0 if xi outside [ximin,ximax)), then loops
// yi = 0..44 writing one nontemporal int4 per iteration. Output slabs for
// consecutive yi are contiguous: tile = xi*45 + yi, out[tile*N + n].
// Reads: 10 MB total. Writes: 472 MB streaming — pure store-bound.
// ---------------------------------------------------------------------------
__global__ void __launch_bounds__(256)
mask_kernel(const uint4* __restrict__ pk, int* __restrict__ out) {
    unsigned int xi = blockIdx.y;                    // 0..79
    int t = blockIdx.x * blockDim.x + threadIdx.x;   // thread index over uint4s
    int n = t * 4;                                   // first point index

    uint4 p = pk[t];
    const unsigned int* pp = &p.x;

    unsigned long long ym[4];
#pragma unroll
    for (int j = 0; j < 4; ++j) {
        unsigned int w = pp[j];
        unsigned int ximin =  w        & 0xFFu;
        unsigned int ximax = (w >> 8)  & 0xFFu;
        unsigned int yimin = (w >> 16) & 0xFFu;
        unsigned int yimax =  w >> 24;
        // bits [yimin, yimax) set; zero if x-range excludes this xi
        unsigned long long m = (1ull << yimax) - (1ull << yimin);
        ym[j] = (xi >= ximin && xi < ximax) ? m : 0ull;
    }

    int* dst = out + ((size_t)xi * NBH) * N_POINTS + n;
#pragma unroll 5
    for (int yi = 0; yi < NBH; ++yi) {
        v4i res;
        res[0] = (int)((ym[0] >> yi) & 1ull);
        res[1] = (int)((ym[1] >> yi) & 1ull);
        res[2] = (int)((ym[2] >> yi) & 1ull);
        res[3] = (int)((ym[3] >> yi) & 1ull);
        __builtin_nontemporal_store(res, (v4i*)dst);
        dst += N_POINTS;   // next tile's slab (+128 KB)
    }
}

extern "C" void kernel_launch(void* const* d_in, const int* in_sizes, int n_in,
                              void* d_out, int out_size, void* d_ws, size_t ws_size,
                              hipStream_t stream) {
    const float* pos2d  = (const float*)d_in[0];
    const float* radius = (const float*)d_in[1];
    int* out = (int*)d_out;
    unsigned int* pk = (unsigned int*)d_ws;   // 32768 * 4 B = 128 KB

    // Kernel A: 32768 points / 4 per thread = 8192 threads
    aabb_kernel<<<dim3(8192 / 256), dim3(256), 0, stream>>>(pos2d, radius, pk);

    // Kernel B: 32 chunks x 80 xi; each block covers 45 yi-tiles
    mask_kernel<<<dim3(32, NBW), dim3(256), 0, stream>>>((const uint4*)pk, out);
}

// Round 6
// 446.425 us; speedup vs baseline: 1.0281x; 1.0281x over previous
//
#include <hip/hip_runtime.h>
#include <hip/hip_bf16.h>

// Problem constants (from reference)
#define SCREEN_W 1280
#define SCREEN_H 720
#define TILE_L   16
#define NBW      80    // ceil(1280/16)
#define NBH      45    // ceil(720/16)
#define NUM_TILE 3600  // 80*45
#define N_POINTS 32768

typedef int v4i __attribute__((ext_vector_type(4)));

// ---------------------------------------------------------------------------
// Kernel A: per-point tile-index ranges packed into one u32:
//   ximin | ximax<<8 | yimin<<16 | yimax<<24   (half-open: ximin <= xi < ximax)
// overlap_x(tile xi) <=> (xmin>>4) <= xi < ((xmax+15)>>4)   [verified: absmax 0]
// Table: 32768 * 4 B = 128 KB in d_ws.
// ---------------------------------------------------------------------------
__global__ void aabb_kernel(const float* __restrict__ pos2d,
                            const float* __restrict__ radius,
                            unsigned int* __restrict__ pk) {
    int t = blockIdx.x * blockDim.x + threadIdx.x;   // thread handles 4 points
    int n = t * 4;
    if (n >= N_POINTS) return;

    const float4* p4 = (const float4*)(pos2d + 2 * n);
    float4 p01 = p4[0];   // x0 y0 x1 y1
    float4 p23 = p4[1];   // x2 y2 x3 y3
    float4 r   = *(const float4*)(radius + n);

    float xs[4] = {p01.x, p01.z, p23.x, p23.z};
    float ys[4] = {p01.y, p01.w, p23.y, p23.w};
    float rs[4] = {r.x, r.y, r.z, r.w};

    uint4 outp;
    unsigned int* op = &outp.x;
#pragma unroll
    for (int j = 0; j < 4; ++j) {
        float x = xs[j], y = ys[j], rr = rs[j];
        int xmin = (int)fminf(fmaxf(x - rr, 0.0f), (float)SCREEN_W);
        int ymin = (int)fminf(fmaxf(y - rr, 0.0f), (float)SCREEN_H);
        int xmax = (int)fminf(fmaxf(x + rr, 0.0f), (float)SCREEN_W);
        int ymax = (int)fminf(fmaxf(y + rr, 0.0f), (float)SCREEN_H);
        unsigned int ximin = (unsigned int)(xmin >> 4);          // <= 80
        unsigned int ximax = (unsigned int)((xmax + 15) >> 4);   // <= 80
        unsigned int yimin = (unsigned int)(ymin >> 4);          // <= 45
        unsigned int yimax = (unsigned int)((ymax + 15) >> 4);   // <= 45
        op[j] = ximin | (ximax << 8) | (yimin << 16) | (yimax << 24);
    }
    *(uint4*)(pk + n) = outp;
}

// ---------------------------------------------------------------------------
// Kernel B (R4 grid, PLAIN store A/B vs R4's nontemporal store):
// tile t (blockIdx.y), point chunk (blockIdx.x). One uint4 load per thread
// (4 packed points), byte-unpack compares vs (xi,yi), ONE plain 16 B store.
// Output layout: out[t * N_POINTS + n]  (tile-major [T, N]).
// ---------------------------------------------------------------------------
__global__ void __launch_bounds__(256)
mask_kernel(const uint4* __restrict__ pk, int* __restrict__ out) {
    int tile = blockIdx.y;
    int t = blockIdx.x * blockDim.x + threadIdx.x;   // thread index over uint4s
    int n = t * 4;                                    // first point index

    unsigned int xi = (unsigned int)(tile / NBH);
    unsigned int yi = (unsigned int)(tile - (int)xi * NBH);

    uint4 p = pk[t];
    const unsigned int* pp = &p.x;

    v4i res;
#pragma unroll
    for (int j = 0; j < 4; ++j) {
        unsigned int w = pp[j];
        unsigned int ximin =  w        & 0xFFu;
        unsigned int ximax = (w >> 8)  & 0xFFu;
        unsigned int yimin = (w >> 16) & 0xFFu;
        unsigned int yimax =  w >> 24;
        res[j] = (xi >= ximin && xi < ximax && yi >= yimin && yi < yimax) ? 1 : 0;
    }

    // PLAIN store (the harness fill reaches 6.35 TB/s with plain stores;
    // A/B against R4's __builtin_nontemporal_store)
    *(v4i*)(out + (size_t)tile * N_POINTS + n) = res;
}

extern "C" void kernel_launch(void* const* d_in, const int* in_sizes, int n_in,
                              void* d_out, int out_size, void* d_ws, size_t ws_size,
                              hipStream_t stream) {
    const float* pos2d  = (const float*)d_in[0];
    const float* radius = (const float*)d_in[1];
    int* out = (int*)d_out;
    unsigned int* pk = (unsigned int*)d_ws;   // 32768 * 4 B = 128 KB

    // Kernel A: 32768 points / 4 per thread = 8192 threads
    aabb_kernel<<<dim3(8192 / 256), dim3(256), 0, stream>>>(pos2d, radius, pk);

    // Kernel B: 32768 / (256*4) = 32 chunks x 3600 tiles
    mask_kernel<<<dim3(32, NUM_TILE), dim3(256), 0, stream>>>((const uint4*)pk, out);
}